// Round 1
// baseline (5468.549 us; speedup 1.0000x reference)
//
#include <hip/hip_runtime.h>

// CTRNN fused kernel. B=512,T=1024,I=64,H=256,C=5, UNFOLDS=6, h=0.9h+0.1*tanh(xw+h@Wh).
// 32 workgroups x 256 threads (4 waves). Each wg owns 16 batch rows, runs the full
// T*6 sequential chain with MFMA 16x16x32 bf16. Wh resident in VGPRs; h in fp32 regs
// + bf16 ping-pong LDS (XOR-swizzled) for A-fragments.

#define T_ 1024
#define I_ 64
#define H_ 256
#define C_ 5

typedef float f32x4 __attribute__((ext_vector_type(4)));
typedef __bf16 bf16x8 __attribute__((ext_vector_type(8)));
typedef unsigned short ushort_t;
typedef ushort_t ushort8 __attribute__((ext_vector_type(8)));

__device__ __forceinline__ ushort_t f2bf(float x) {
  unsigned u = __builtin_bit_cast(unsigned, x);
  return (ushort_t)((u + 0x7FFFu + ((u >> 16) & 1u)) >> 16);  // RNE
}
__device__ __forceinline__ float fast_tanh_(float v) {
  float e = __expf(v + v);                       // e^{2v}
  return 1.0f - 2.0f * __builtin_amdgcn_rcpf(e + 1.0f);
}
#define MFMA(a, b, c) __builtin_amdgcn_mfma_f32_16x16x32_bf16((a), (b), (c), 0, 0, 0)

__launch_bounds__(256, 1)
__global__ void ctrnn_fused(const float* __restrict__ x, const float* __restrict__ W,
                            const float* __restrict__ bh, const float* __restrict__ Wfc,
                            const float* __restrict__ bfc, float* __restrict__ out) {
  // LDS: h ping-pong [2][16 rows][256 cols] bf16, swizzled byte^=(row&7)<<4
  __shared__ __align__(16) char hbuf[2][16 * 256 * 2];
  __shared__ __align__(16) char xls[16 * 64 * 2];
  __shared__ float red[4][16][C_];

  const int tid = threadIdx.x;
  const int w   = tid >> 6;   // wave 0..3, owns output cols [64w, 64w+64)
  const int l   = tid & 63;
  const int lr  = l & 15;     // MFMA row (A) / col (B,C)
  const int lq  = l >> 4;     // quad
  const int b0  = blockIdx.x << 4;

  // ---- resident fragments (loaded once) ----
  bf16x8 wh[8][4];   // Wh[k][n]: kt=K/32 tile, s=16-col subtile of this wave's 64
  bf16x8 wx[2][4];   // Wx[i][n]
  bf16x8 wf[2];      // Wfc[k][c] for this wave's K range [64w,64w+64), cols padded to 16
  float bia[4];

#pragma unroll
  for (int kt = 0; kt < 8; ++kt)
#pragma unroll
    for (int s = 0; s < 4; ++s) {
      ushort8 tmp;
#pragma unroll
      for (int j = 0; j < 8; ++j) {
        int k = kt * 32 + lq * 8 + j;
        int col = w * 64 + s * 16 + lr;
        tmp[j] = f2bf(W[(size_t)(I_ + k) * H_ + col]);
      }
      wh[kt][s] = __builtin_bit_cast(bf16x8, tmp);
    }
#pragma unroll
  for (int kt = 0; kt < 2; ++kt)
#pragma unroll
    for (int s = 0; s < 4; ++s) {
      ushort8 tmp;
#pragma unroll
      for (int j = 0; j < 8; ++j) {
        int k = kt * 32 + lq * 8 + j;
        int col = w * 64 + s * 16 + lr;
        tmp[j] = f2bf(W[(size_t)k * H_ + col]);
      }
      wx[kt][s] = __builtin_bit_cast(bf16x8, tmp);
    }
#pragma unroll
  for (int kt = 0; kt < 2; ++kt) {
    ushort8 tmp;
#pragma unroll
    for (int j = 0; j < 8; ++j) {
      int k = w * 64 + kt * 32 + lq * 8 + j;
      tmp[j] = (lr < C_) ? f2bf(Wfc[(size_t)k * C_ + lr]) : (ushort_t)0;
    }
    wf[kt] = __builtin_bit_cast(bf16x8, tmp);
  }
#pragma unroll
  for (int s = 0; s < 4; ++s) bia[s] = bh[w * 64 + s * 16 + lr];

  // zero h buffer 0 (initial state)
  for (int i = tid; i < 16 * 256; i += 256) ((ushort_t*)hbuf[0])[i] = 0;

  // x prefetch for t=0: thread -> (row=tid>>4, float4 chunk=tid&15)
  const int xrow = tid >> 4, xc = tid & 15;
  const float* xbase = x + (size_t)(b0 + xrow) * T_ * I_ + xc * 4;
  float4 xpre = *(const float4*)(xbase);

  __syncthreads();

  f32x4 h[4];  // fp32 recurrent state, rows lq*4+j, cols 64w+16s+lr
#pragma unroll
  for (int s = 0; s < 4; ++s) h[s] = (f32x4){0.f, 0.f, 0.f, 0.f};

#pragma unroll 1
  for (int t = 0; t < T_; ++t) {
    // ---- stage x tile (16x64 bf16, swizzled) ----
    {
      int byte = xrow * 128 + xc * 8;
      byte ^= (xrow & 7) << 4;
      uint2 pk;
      pk.x = (unsigned)f2bf(xpre.x) | ((unsigned)f2bf(xpre.y) << 16);
      pk.y = (unsigned)f2bf(xpre.z) | ((unsigned)f2bf(xpre.w) << 16);
      *(uint2*)(xls + byte) = pk;
    }
    __syncthreads();

    // ---- xw = x @ Wx + b (acc init = bias) ----
    f32x4 xw[4];
    {
      bf16x8 xa[2];
#pragma unroll
      for (int kt = 0; kt < 2; ++kt) {
        int byte = lr * 128 + (kt * 32 + lq * 8) * 2;
        byte ^= (lr & 7) << 4;
        xa[kt] = *(const bf16x8*)(xls + byte);
      }
#pragma unroll
      for (int s = 0; s < 4; ++s) {
        f32x4 a = (f32x4){bia[s], bia[s], bia[s], bia[s]};
        a = MFMA(xa[0], wx[0][s], a);
        a = MFMA(xa[1], wx[1][s], a);
        xw[s] = a;
      }
    }
    // prefetch next x tile while unfolds run
    if (t + 1 < T_) xpre = *(const float4*)(xbase + (size_t)(t + 1) * I_);

    // ---- 6 unfolds ----
#pragma unroll
    for (int u = 0; u < 6; ++u) {
      const char* hb = hbuf[u & 1];
      bf16x8 ha[8];
#pragma unroll
      for (int kt = 0; kt < 8; ++kt) {
        int byte = lr * 512 + (kt * 32 + lq * 8) * 2;
        byte ^= (lr & 7) << 4;
        ha[kt] = *(const bf16x8*)(hb + byte);
      }
      f32x4 acc[4];
#pragma unroll
      for (int s = 0; s < 4; ++s) acc[s] = xw[s];
#pragma unroll
      for (int kt = 0; kt < 8; ++kt)
#pragma unroll
        for (int s = 0; s < 4; ++s) acc[s] = MFMA(ha[kt], wh[kt][s], acc[s]);

      char* hw = hbuf[(u + 1) & 1];
#pragma unroll
      for (int s = 0; s < 4; ++s)
#pragma unroll
        for (int j = 0; j < 4; ++j) {
          float f = fast_tanh_(acc[s][j]);
          float hn = 0.9f * h[s][j] + 0.1f * f;
          h[s][j] = hn;
          int row = lq * 4 + j, col = w * 64 + s * 16 + lr;
          int byte = row * 512 + col * 2;
          byte ^= (row & 7) << 4;
          *(ushort_t*)(hw + byte) = f2bf(hn);
        }
      __syncthreads();
    }

    // ---- logits: this wave handles K chunk [64w, 64w+64) ----
    {
      bf16x8 hA0, hA1;
      {
        int byte = lr * 512 + ((2 * w) * 32 + lq * 8) * 2;
        byte ^= (lr & 7) << 4;
        hA0 = *(const bf16x8*)(hbuf[0] + byte);
        byte = lr * 512 + ((2 * w + 1) * 32 + lq * 8) * 2;
        byte ^= (lr & 7) << 4;
        hA1 = *(const bf16x8*)(hbuf[0] + byte);
      }
      f32x4 part = (f32x4){0.f, 0.f, 0.f, 0.f};
      part = MFMA(hA0, wf[0], part);
      part = MFMA(hA1, wf[1], part);
      if (lr < C_) {
#pragma unroll
        for (int j = 0; j < 4; ++j) red[w][lq * 4 + j][lr] = part[j];
      }
    }
    __syncthreads();
    if (tid < 16 * C_) {
      int r = tid / C_, c = tid - r * C_;
      float sum = red[0][r][c] + red[1][r][c] + red[2][r][c] + red[3][r][c] + bfc[c];
      out[((size_t)(b0 + r) * C_ + c) * T_ + t] = sum;
    }
    // no barrier needed: next writers of red/xls are separated by >=7 barriers
  }
}

extern "C" void kernel_launch(void* const* d_in, const int* in_sizes, int n_in,
                              void* d_out, int out_size, void* d_ws, size_t ws_size,
                              hipStream_t stream) {
  const float* x   = (const float*)d_in[0];
  const float* W   = (const float*)d_in[1];
  const float* bh  = (const float*)d_in[2];
  const float* Wfc = (const float*)d_in[3];
  const float* bfc = (const float*)d_in[4];
  float* out = (float*)d_out;
  (void)in_sizes; (void)n_in; (void)out_size; (void)d_ws; (void)ws_size;
  ctrnn_fused<<<dim3(32), dim3(256), 0, stream>>>(x, W, bh, Wfc, bfc, out);
}